// Round 3
// baseline (216793.994 us; speedup 1.0000x reference)
//
#include <hip/hip_runtime.h>
#include <hip/hip_cooperative_groups.h>
#include <cmath>

namespace cg = cooperative_groups;

#define TSEQ 2048
#define H    1024
#define L    4
#define WPL  64          // workgroups per layer
#define NWG  (WPL * L)   // 256 blocks = 1 per CU
#define NTH  512         // 8 waves per block

__device__ __forceinline__ float waveSum(float v) {
#pragma unroll
  for (int off = 32; off > 0; off >>= 1) v += __shfl_xor(v, off, 64);
  return v;
}

__device__ __forceinline__ float sigmoidf_(float x) {
  return 1.0f / (1.0f + expf(-x));
}

// Diagonal-wavefront persistent LSTM. At global step k, layer l processes
// t = k - l; all 4 layers run concurrently on 64 blocks each.
// Layer 0's "U-side" matvec uses the input projection U_g @ x_t (same shape
// as UH_g @ h_below), so every block does exactly 8 H-wide matvec rows per
// step and no precomputed Z scratch is needed (ws usage = 32 KB hbuf only).
__global__ __launch_bounds__(NTH) void lstm_seq(
    const float* __restrict__ X,                                   // [TSEQ][H]
    const float* __restrict__ Uf,  const float* __restrict__ Ug,   // [H][H]
    const float* __restrict__ Uq,  const float* __restrict__ Uc,
    const float* __restrict__ UHf, const float* __restrict__ UHg,  // [L-1][H][H]
    const float* __restrict__ UHq, const float* __restrict__ UHc,
    const float* __restrict__ Wf,  const float* __restrict__ Wg,   // [L][H][H]
    const float* __restrict__ Wq,  const float* __restrict__ Wc,
    const float* __restrict__ Bf,  const float* __restrict__ Bg,   // [L][H]
    const float* __restrict__ Bq,  const float* __restrict__ Bc,
    float* __restrict__ hbuf,   // ws: [2][L][H] double-buffered hidden state
    float* __restrict__ out)    // [L][H]
{
  cg::grid_group grid = cg::this_grid();
  const int tid  = threadIdx.x;
  const int lane = tid & 63;
  const int wv   = tid >> 6;            // wave 0..7
  const int l    = blockIdx.x >> 6;     // layer 0..3
  const int wgl  = blockIdx.x & 63;     // block index within layer

  // d_ws is poisoned 0xAA before every timed call: zero the h state.
  for (int i = blockIdx.x * NTH + tid; i < 2 * L * H; i += NWG * NTH)
    hbuf[i] = 0.0f;

  const size_t lHH = (size_t)l * H * H;
  const float* Wp[4] = { Wf + lHH, Wg + lHH, Wq + lHH, Wc + lHH };
  const float* Up[4];
  if (l == 0) {
    Up[0] = Uf; Up[1] = Ug; Up[2] = Uq; Up[3] = Uc;
  } else {
    const size_t o = (size_t)(l - 1) * H * H;
    Up[0] = UHf + o; Up[1] = UHg + o; Up[2] = UHq + o; Up[3] = UHc + o;
  }
  const float* Bp[4] = { Bf + (size_t)l * H, Bg + (size_t)l * H,
                         Bq + (size_t)l * H, Bc + (size_t)l * H };

  __shared__ float4 hA4[H / 4];  // own h(t-1)
  __shared__ float4 hB4[H / 4];  // layer-0: x_t ; layers 1-3: h_below(t)
  float* hA = (float*)hA4;
  float* hB = (float*)hB4;

  float sreg[2] = {0.0f, 0.0f};  // cell state for this wave's 2 rows

  __threadfence();
  grid.sync();

  for (int k = 0; k < TSEQ + L - 1; ++k) {
    const int t = k - l;
    if (0 <= t && t < TSEQ) {
      const float* hprev = hbuf + ((size_t)((t - 1) & 1) * L + l) * H;
      const float* xin = (l == 0)
          ? (X + (size_t)t * H)
          : (hbuf + ((size_t)(t & 1) * L + (l - 1)) * H);
      for (int i = tid; i < H; i += NTH) { hA[i] = hprev[i]; hB[i] = xin[i]; }
      __syncthreads();

#pragma unroll
      for (int ri = 0; ri < 2; ++ri) {
        const int r = wgl * 16 + wv * 2 + ri;
        float a0 = 0.f, a1 = 0.f, a2 = 0.f, a3 = 0.f;
        const float4* w0 = (const float4*)(Wp[0] + (size_t)r * H);
        const float4* w1 = (const float4*)(Wp[1] + (size_t)r * H);
        const float4* w2 = (const float4*)(Wp[2] + (size_t)r * H);
        const float4* w3 = (const float4*)(Wp[3] + (size_t)r * H);
        const float4* u0 = (const float4*)(Up[0] + (size_t)r * H);
        const float4* u1 = (const float4*)(Up[1] + (size_t)r * H);
        const float4* u2 = (const float4*)(Up[2] + (size_t)r * H);
        const float4* u3 = (const float4*)(Up[3] + (size_t)r * H);
#pragma unroll
        for (int j = 0; j < 4; ++j) {
          const int c = lane + 64 * j;
          float4 hv = hA4[c];
          float4 m0 = w0[c], m1 = w1[c], m2 = w2[c], m3 = w3[c];
          a0 = fmaf(m0.x, hv.x, a0); a0 = fmaf(m0.y, hv.y, a0);
          a0 = fmaf(m0.z, hv.z, a0); a0 = fmaf(m0.w, hv.w, a0);
          a1 = fmaf(m1.x, hv.x, a1); a1 = fmaf(m1.y, hv.y, a1);
          a1 = fmaf(m1.z, hv.z, a1); a1 = fmaf(m1.w, hv.w, a1);
          a2 = fmaf(m2.x, hv.x, a2); a2 = fmaf(m2.y, hv.y, a2);
          a2 = fmaf(m2.z, hv.z, a2); a2 = fmaf(m2.w, hv.w, a2);
          a3 = fmaf(m3.x, hv.x, a3); a3 = fmaf(m3.y, hv.y, a3);
          a3 = fmaf(m3.w, hv.w, a3); a3 = fmaf(m3.z, hv.z, a3);
          float4 xv = hB4[c];
          float4 n0 = u0[c], n1 = u1[c], n2 = u2[c], n3 = u3[c];
          a0 = fmaf(n0.x, xv.x, a0); a0 = fmaf(n0.y, xv.y, a0);
          a0 = fmaf(n0.z, xv.z, a0); a0 = fmaf(n0.w, xv.w, a0);
          a1 = fmaf(n1.x, xv.x, a1); a1 = fmaf(n1.y, xv.y, a1);
          a1 = fmaf(n1.z, xv.z, a1); a1 = fmaf(n1.w, xv.w, a1);
          a2 = fmaf(n2.x, xv.x, a2); a2 = fmaf(n2.y, xv.y, a2);
          a2 = fmaf(n2.z, xv.z, a2); a2 = fmaf(n2.w, xv.w, a2);
          a3 = fmaf(n3.x, xv.x, a3); a3 = fmaf(n3.y, xv.y, a3);
          a3 = fmaf(n3.z, xv.z, a3); a3 = fmaf(n3.w, xv.w, a3);
        }
        a0 = waveSum(a0); a1 = waveSum(a1);
        a2 = waveSum(a2); a3 = waveSum(a3);
        float f  = sigmoidf_(Bp[0][r] + a0);
        float g  = sigmoidf_(Bp[1][r] + a1);
        float q  = sigmoidf_(Bp[2][r] + a2);
        float cd = sigmoidf_(Bp[3][r] + a3);
        float sN = f * sreg[ri] + g * cd;
        sreg[ri] = sN;
        float hN = tanhf(sN) * q;
        if (lane == 0) {
          hbuf[((size_t)(t & 1) * L + l) * H + r] = hN;
          if (t == TSEQ - 1) out[(size_t)l * H + r] = hN;
        }
      }
    }
    __threadfence();
    grid.sync();
  }
}

// ---------------- launch ----------------------------------------------------
extern "C" void kernel_launch(void* const* d_in, const int* in_sizes, int n_in,
                              void* d_out, int out_size, void* d_ws, size_t ws_size,
                              hipStream_t stream) {
  const float* x   = (const float*)d_in[0];
  const float* Uf  = (const float*)d_in[1];
  const float* UHf = (const float*)d_in[2];
  const float* Wf  = (const float*)d_in[3];
  const float* Bf  = (const float*)d_in[4];
  const float* Ug  = (const float*)d_in[5];
  const float* UHg = (const float*)d_in[6];
  const float* Wg  = (const float*)d_in[7];
  const float* Bg  = (const float*)d_in[8];
  const float* Uq  = (const float*)d_in[9];
  const float* UHq = (const float*)d_in[10];
  const float* Wq  = (const float*)d_in[11];
  const float* Bq  = (const float*)d_in[12];
  const float* Uc  = (const float*)d_in[13];
  const float* UHc = (const float*)d_in[14];
  const float* Wc  = (const float*)d_in[15];
  const float* Bc  = (const float*)d_in[16];
  float* out = (float*)d_out;

  float* hbuf = (float*)d_ws;  // [2][L][H] = 32 KB, only ws usage

  void* args[] = { (void*)&x,
                   (void*)&Uf, (void*)&Ug, (void*)&Uq, (void*)&Uc,
                   (void*)&UHf, (void*)&UHg, (void*)&UHq, (void*)&UHc,
                   (void*)&Wf, (void*)&Wg, (void*)&Wq, (void*)&Wc,
                   (void*)&Bf, (void*)&Bg, (void*)&Bq, (void*)&Bc,
                   (void*)&hbuf, (void*)&out };
  hipLaunchCooperativeKernel(reinterpret_cast<void*>(lstm_seq),
                             dim3(NWG), dim3(NTH), args, 0, stream);
}

// Round 4
// 146273.962 us; speedup vs baseline: 1.4821x; 1.4821x over previous
//
#include <hip/hip_runtime.h>
#include <hip/hip_cooperative_groups.h>
#include <cmath>

namespace cg = cooperative_groups;

#define TSEQ 2048
#define H    1024
#define L    4
#define WPL  64          // workgroups per layer
#define NWG  (WPL * L)   // 256 blocks = 1 per CU
#define NTH  512         // 8 waves per block -> 2 waves/SIMD, VGPR cap 256

__device__ __forceinline__ float waveSum(float v) {
#pragma unroll
  for (int off = 32; off > 0; off >>= 1) v += __shfl_xor(v, off, 64);
  return v;
}

__device__ __forceinline__ float sigmoidf_(float x) {
  return 1.0f / (1.0f + __expf(-x));
}

__device__ __forceinline__ unsigned bf16rne(float f) {
  unsigned u = __float_as_uint(f);
  return (u + 0x7fffu + ((u >> 16) & 1u)) >> 16;
}

// Persistent-register-weight diagonal-wavefront LSTM.
// All 32M weight elements live in VGPRs as bf16 (64 MB chip-wide = 50% of the
// VGPR file): each lane owns 16 contiguous columns of 16 matrix rows
// (2 output rows x 8 matrices), packed 2xbf16 per reg = 128 VGPRs.
// Weights are fetched from HBM exactly once; per step a lane reads only
// 128 B of h-vectors (L2-hot) and does ~512 VALU ops.
__global__ __launch_bounds__(NTH, 2) void lstm_seq(
    const float* __restrict__ X,                                   // [TSEQ][H]
    const float* __restrict__ Uf,  const float* __restrict__ Ug,   // [H][H]
    const float* __restrict__ Uq,  const float* __restrict__ Uc,
    const float* __restrict__ UHf, const float* __restrict__ UHg,  // [L-1][H][H]
    const float* __restrict__ UHq, const float* __restrict__ UHc,
    const float* __restrict__ Wf,  const float* __restrict__ Wg,   // [L][H][H]
    const float* __restrict__ Wq,  const float* __restrict__ Wc,
    const float* __restrict__ Bf,  const float* __restrict__ Bg,   // [L][H]
    const float* __restrict__ Bq,  const float* __restrict__ Bc,
    float* __restrict__ hbuf,   // ws: [2][L][H] double-buffered hidden state
    float* __restrict__ out)    // [L][H]
{
  cg::grid_group grid = cg::this_grid();
  const int tid  = threadIdx.x;
  const int lane = tid & 63;
  const int wv   = tid >> 6;            // wave 0..7
  const int l    = blockIdx.x >> 6;     // layer 0..3
  const int wgl  = blockIdx.x & 63;     // block index within layer
  const int r0   = wgl * 16 + wv * 2;   // this wave's 2 output rows
  const int colBase = lane * 16;        // this lane's 16 contiguous columns

  // d_ws is poisoned 0xAA before every timed call: zero the h state.
  for (int i = blockIdx.x * NTH + tid; i < 2 * L * H; i += NWG * NTH)
    hbuf[i] = 0.0f;

  // ---- matrix pointers: 0..3 = W-side (recurrent), 4..7 = U-side ----------
  const size_t lHH = (size_t)l * H * H;
  const float* Mp[8];
  Mp[0] = Wf + lHH; Mp[1] = Wg + lHH; Mp[2] = Wq + lHH; Mp[3] = Wc + lHH;
  if (l == 0) {
    Mp[4] = Uf; Mp[5] = Ug; Mp[6] = Uq; Mp[7] = Uc;
  } else {
    const size_t o = (size_t)(l - 1) * H * H;
    Mp[4] = UHf + o; Mp[5] = UHg + o; Mp[6] = UHq + o; Mp[7] = UHc + o;
  }

  // ---- one-time weight fetch -> bf16x2 packed registers (128 VGPRs) -------
  unsigned wpk[8][2][8];
#pragma unroll
  for (int mi = 0; mi < 8; ++mi)
#pragma unroll
    for (int ri = 0; ri < 2; ++ri) {
      const float* rowp = Mp[mi] + (size_t)(r0 + ri) * H + colBase;
#pragma unroll
      for (int q = 0; q < 4; ++q) {
        float4 w4 = *(const float4*)(rowp + 4 * q);
        wpk[mi][ri][2 * q]     = bf16rne(w4.x) | (bf16rne(w4.y) << 16);
        wpk[mi][ri][2 * q + 1] = bf16rne(w4.z) | (bf16rne(w4.w) << 16);
      }
    }

  float bias[4][2];
#pragma unroll
  for (int ri = 0; ri < 2; ++ri) {
    bias[0][ri] = Bf[(size_t)l * H + r0 + ri];
    bias[1][ri] = Bg[(size_t)l * H + r0 + ri];
    bias[2][ri] = Bq[(size_t)l * H + r0 + ri];
    bias[3][ri] = Bc[(size_t)l * H + r0 + ri];
  }

  float sreg[2] = {0.0f, 0.0f};  // cell state for this wave's 2 rows

  __threadfence();
  grid.sync();

  for (int k = 0; k < TSEQ + L - 1; ++k) {
    const int t = k - l;
    if (0 <= t && t < TSEQ) {
      const float* hprev = hbuf + ((size_t)((t - 1) & 1) * L + l) * H + colBase;
      const float* xin = ((l == 0)
          ? (X + (size_t)t * H)
          : (hbuf + ((size_t)(t & 1) * L + (l - 1)) * H)) + colBase;

      float ha[16], hb[16];
#pragma unroll
      for (int q = 0; q < 4; ++q) {
        float4 a4 = *(const float4*)(hprev + 4 * q);
        float4 b4 = *(const float4*)(xin + 4 * q);
        ha[4 * q] = a4.x; ha[4 * q + 1] = a4.y; ha[4 * q + 2] = a4.z; ha[4 * q + 3] = a4.w;
        hb[4 * q] = b4.x; hb[4 * q + 1] = b4.y; hb[4 * q + 2] = b4.z; hb[4 * q + 3] = b4.w;
      }

      float acc[4][2];
#pragma unroll
      for (int g = 0; g < 4; ++g)
#pragma unroll
        for (int ri = 0; ri < 2; ++ri) {
          float a = 0.0f;
#pragma unroll
          for (int jj = 0; jj < 8; ++jj) {
            const unsigned wA = wpk[g][ri][jj];        // W-side (recurrent)
            a = fmaf(__uint_as_float(wA << 16),        ha[2 * jj],     a);
            a = fmaf(__uint_as_float(wA & 0xffff0000u), ha[2 * jj + 1], a);
            const unsigned wB = wpk[4 + g][ri][jj];    // U-side (input/below)
            a = fmaf(__uint_as_float(wB << 16),        hb[2 * jj],     a);
            a = fmaf(__uint_as_float(wB & 0xffff0000u), hb[2 * jj + 1], a);
          }
          acc[g][ri] = a;
        }

#pragma unroll
      for (int g = 0; g < 4; ++g)
#pragma unroll
        for (int ri = 0; ri < 2; ++ri) acc[g][ri] = waveSum(acc[g][ri]);

#pragma unroll
      for (int ri = 0; ri < 2; ++ri) {
        float f  = sigmoidf_(bias[0][ri] + acc[0][ri]);
        float g_ = sigmoidf_(bias[1][ri] + acc[1][ri]);
        float q_ = sigmoidf_(bias[2][ri] + acc[2][ri]);
        float cd = sigmoidf_(bias[3][ri] + acc[3][ri]);
        float sN = f * sreg[ri] + g_ * cd;
        sreg[ri] = sN;
        float hN = tanhf(sN) * q_;
        if (lane == ri) {
          hbuf[((size_t)(t & 1) * L + l) * H + r0 + ri] = hN;
          if (t == TSEQ - 1) out[(size_t)l * H + r0 + ri] = hN;
        }
      }
    }
    __threadfence();
    grid.sync();
  }
}

// ---------------- launch ----------------------------------------------------
extern "C" void kernel_launch(void* const* d_in, const int* in_sizes, int n_in,
                              void* d_out, int out_size, void* d_ws, size_t ws_size,
                              hipStream_t stream) {
  const float* x   = (const float*)d_in[0];
  const float* Uf  = (const float*)d_in[1];
  const float* UHf = (const float*)d_in[2];
  const float* Wf  = (const float*)d_in[3];
  const float* Bf  = (const float*)d_in[4];
  const float* Ug  = (const float*)d_in[5];
  const float* UHg = (const float*)d_in[6];
  const float* Wg  = (const float*)d_in[7];
  const float* Bg  = (const float*)d_in[8];
  const float* Uq  = (const float*)d_in[9];
  const float* UHq = (const float*)d_in[10];
  const float* Wq  = (const float*)d_in[11];
  const float* Bq  = (const float*)d_in[12];
  const float* Uc  = (const float*)d_in[13];
  const float* UHc = (const float*)d_in[14];
  const float* Wc  = (const float*)d_in[15];
  const float* Bc  = (const float*)d_in[16];
  float* out = (float*)d_out;

  float* hbuf = (float*)d_ws;  // [2][L][H] = 32 KB, only ws usage

  void* args[] = { (void*)&x,
                   (void*)&Uf, (void*)&Ug, (void*)&Uq, (void*)&Uc,
                   (void*)&UHf, (void*)&UHg, (void*)&UHq, (void*)&UHc,
                   (void*)&Wf, (void*)&Wg, (void*)&Wq, (void*)&Wc,
                   (void*)&Bf, (void*)&Bg, (void*)&Bq, (void*)&Bc,
                   (void*)&hbuf, (void*)&out };
  hipLaunchCooperativeKernel(reinterpret_cast<void*>(lstm_seq),
                             dim3(NWG), dim3(NTH), args, 0, stream);
}

// Round 5
// 93961.902 us; speedup vs baseline: 2.3073x; 1.5567x over previous
//
#include <hip/hip_runtime.h>
#include <hip/hip_cooperative_groups.h>
#include <cmath>

namespace cg = cooperative_groups;

#define TSEQ 2048
#define H    1024
#define L    4
#define WPL  64          // workgroups per layer
#define NWG  (WPL * L)   // 256 blocks = 1 per CU
#define NTH  512         // 8 waves per block

__device__ __forceinline__ float waveSum(float v) {
#pragma unroll
  for (int off = 32; off > 0; off >>= 1) v += __shfl_xor(v, off, 64);
  return v;
}

__device__ __forceinline__ float sigmoidf_(float x) {
  return 1.0f / (1.0f + __expf(-x));
}

__device__ __forceinline__ unsigned bf16rne(float f) {
  unsigned u = __float_as_uint(f);
  return (u + 0x7fffu + ((u >> 16) & 1u)) >> 16;
}

__device__ __forceinline__ unsigned ldAgent(const unsigned* p) {
  return __hip_atomic_load(p, __ATOMIC_RELAXED, __HIP_MEMORY_SCOPE_AGENT);
}

// Persistent-register-weight LSTM with decentralized dataflow sync.
// Weights (64 MB as bf16) live in the chip's register file; fetched once.
// Sync: prog[l][wgl] = number of completed timesteps of that block. Block
// (l,wgl) may start step t when:
//   own   : prog[l][*]   >= t      (h_l(t-1) complete)
//   below : prog[l-1][*] >= t+1    (h_{l-1}(t) complete)          [l>0]
//   WAR   : prog[l+1][*] >= t-1    (h_l(t-2) fully consumed)      [l<L-1]
// Wave 0 spins lane-parallel (lane i watches block i's slot); no grid.sync
// in the hot loop.
__global__ __launch_bounds__(NTH, 2) void lstm_seq(
    const float* __restrict__ X,                                   // [TSEQ][H]
    const float* __restrict__ Uf,  const float* __restrict__ Ug,   // [H][H]
    const float* __restrict__ Uq,  const float* __restrict__ Uc,
    const float* __restrict__ UHf, const float* __restrict__ UHg,  // [L-1][H][H]
    const float* __restrict__ UHq, const float* __restrict__ UHc,
    const float* __restrict__ Wf,  const float* __restrict__ Wg,   // [L][H][H]
    const float* __restrict__ Wq,  const float* __restrict__ Wc,
    const float* __restrict__ Bf,  const float* __restrict__ Bg,   // [L][H]
    const float* __restrict__ Bq,  const float* __restrict__ Bc,
    float* __restrict__ hbuf,     // ws: [2][L][H] double-buffered hidden state
    unsigned* __restrict__ prog,  // ws: [L][WPL] progress slots
    float* __restrict__ out)      // [L][H]
{
  cg::grid_group grid = cg::this_grid();
  const int tid  = threadIdx.x;
  const int lane = tid & 63;
  const int wv   = tid >> 6;            // wave 0..7
  const int l    = blockIdx.x >> 6;     // layer 0..3
  const int wgl  = blockIdx.x & 63;     // block index within layer
  const int r0   = wgl * 16 + wv * 2;   // this wave's 2 output rows
  const int colBase = lane * 16;        // this lane's 16 contiguous columns

  // d_ws is poisoned 0xAA before every timed call: zero h state + slots.
  {
    const int gtid = blockIdx.x * NTH + tid;
    for (int i = gtid; i < 2 * L * H; i += NWG * NTH) hbuf[i] = 0.0f;
    for (int i = gtid; i < L * WPL; i += NWG * NTH) prog[i] = 0u;
  }

  // ---- matrix pointers: 0..3 = W-side (recurrent), 4..7 = U-side ----------
  const size_t lHH = (size_t)l * H * H;
  const float* Mp[8];
  Mp[0] = Wf + lHH; Mp[1] = Wg + lHH; Mp[2] = Wq + lHH; Mp[3] = Wc + lHH;
  if (l == 0) {
    Mp[4] = Uf; Mp[5] = Ug; Mp[6] = Uq; Mp[7] = Uc;
  } else {
    const size_t o = (size_t)(l - 1) * H * H;
    Mp[4] = UHf + o; Mp[5] = UHg + o; Mp[6] = UHq + o; Mp[7] = UHc + o;
  }

  // ---- one-time weight fetch -> bf16x2 packed registers (128 regs) --------
  unsigned wpk[8][2][8];
#pragma unroll
  for (int mi = 0; mi < 8; ++mi)
#pragma unroll
    for (int ri = 0; ri < 2; ++ri) {
      const float* rowp = Mp[mi] + (size_t)(r0 + ri) * H + colBase;
#pragma unroll
      for (int q = 0; q < 4; ++q) {
        float4 w4 = *(const float4*)(rowp + 4 * q);
        wpk[mi][ri][2 * q]     = bf16rne(w4.x) | (bf16rne(w4.y) << 16);
        wpk[mi][ri][2 * q + 1] = bf16rne(w4.z) | (bf16rne(w4.w) << 16);
      }
    }

  float bias[4][2];
#pragma unroll
  for (int ri = 0; ri < 2; ++ri) {
    bias[0][ri] = Bf[(size_t)l * H + r0 + ri];
    bias[1][ri] = Bg[(size_t)l * H + r0 + ri];
    bias[2][ri] = Bq[(size_t)l * H + r0 + ri];
    bias[3][ri] = Bc[(size_t)l * H + r0 + ri];
  }

  float sreg[2] = {0.0f, 0.0f};  // cell state for this wave's 2 rows

  __threadfence();
  grid.sync();   // one-time: hbuf/prog zeroing visible everywhere

  for (int t = 0; t < TSEQ; ++t) {
    // ---- dataflow gate: wave 0 spins lane-parallel on progress slots ------
    if (wv == 0) {
      for (;;) {
        bool c = true;
        if (t > 0)
          c = (ldAgent(&prog[l * WPL + lane]) >= (unsigned)t);
        if (l > 0)
          c = c && (ldAgent(&prog[(l - 1) * WPL + lane]) >= (unsigned)(t + 1));
        if (l < L - 1 && t >= 2)
          c = c && (ldAgent(&prog[(l + 1) * WPL + lane]) >= (unsigned)(t - 1));
        if (__all(c)) break;
        __builtin_amdgcn_s_sleep(1);
      }
    }
    __syncthreads();
    __builtin_amdgcn_fence(__ATOMIC_ACQUIRE, "agent");  // invalidate stale h

    const float* hprev = hbuf + ((size_t)((t - 1) & 1) * L + l) * H + colBase;
    const float* xin = ((l == 0)
        ? (X + (size_t)t * H)
        : (hbuf + ((size_t)(t & 1) * L + (l - 1)) * H)) + colBase;

    float ha[16], hb[16];
#pragma unroll
    for (int q = 0; q < 4; ++q) {
      float4 a4 = *(const float4*)(hprev + 4 * q);
      float4 b4 = *(const float4*)(xin + 4 * q);
      ha[4 * q] = a4.x; ha[4 * q + 1] = a4.y; ha[4 * q + 2] = a4.z; ha[4 * q + 3] = a4.w;
      hb[4 * q] = b4.x; hb[4 * q + 1] = b4.y; hb[4 * q + 2] = b4.z; hb[4 * q + 3] = b4.w;
    }

    float acc[4][2];
#pragma unroll
    for (int g = 0; g < 4; ++g)
#pragma unroll
      for (int ri = 0; ri < 2; ++ri) {
        float a = 0.0f;
#pragma unroll
        for (int jj = 0; jj < 8; ++jj) {
          const unsigned wA = wpk[g][ri][jj];        // W-side (recurrent)
          a = fmaf(__uint_as_float(wA << 16),         ha[2 * jj],     a);
          a = fmaf(__uint_as_float(wA & 0xffff0000u), ha[2 * jj + 1], a);
          const unsigned wB = wpk[4 + g][ri][jj];    // U-side (input/below)
          a = fmaf(__uint_as_float(wB << 16),         hb[2 * jj],     a);
          a = fmaf(__uint_as_float(wB & 0xffff0000u), hb[2 * jj + 1], a);
        }
        acc[g][ri] = a;
      }

#pragma unroll
    for (int g = 0; g < 4; ++g)
#pragma unroll
      for (int ri = 0; ri < 2; ++ri) acc[g][ri] = waveSum(acc[g][ri]);

#pragma unroll
    for (int ri = 0; ri < 2; ++ri) {
      float f  = sigmoidf_(bias[0][ri] + acc[0][ri]);
      float g_ = sigmoidf_(bias[1][ri] + acc[1][ri]);
      float q_ = sigmoidf_(bias[2][ri] + acc[2][ri]);
      float cd = sigmoidf_(bias[3][ri] + acc[3][ri]);
      float sN = f * sreg[ri] + g_ * cd;
      sreg[ri] = sN;
      float hN = tanhf(sN) * q_;
      if (lane == ri) {
        hbuf[((size_t)(t & 1) * L + l) * H + r0 + ri] = hN;
        if (t == TSEQ - 1) out[(size_t)l * H + r0 + ri] = hN;
      }
    }

    __builtin_amdgcn_fence(__ATOMIC_RELEASE, "agent");  // flush h stores
    __syncthreads();                                    // all waves flushed
    if (tid == 0)
      __hip_atomic_store(&prog[l * WPL + wgl], (unsigned)(t + 1),
                         __ATOMIC_RELAXED, __HIP_MEMORY_SCOPE_AGENT);
  }
}

// ---------------- launch ----------------------------------------------------
extern "C" void kernel_launch(void* const* d_in, const int* in_sizes, int n_in,
                              void* d_out, int out_size, void* d_ws, size_t ws_size,
                              hipStream_t stream) {
  const float* x   = (const float*)d_in[0];
  const float* Uf  = (const float*)d_in[1];
  const float* UHf = (const float*)d_in[2];
  const float* Wf  = (const float*)d_in[3];
  const float* Bf  = (const float*)d_in[4];
  const float* Ug  = (const float*)d_in[5];
  const float* UHg = (const float*)d_in[6];
  const float* Wg  = (const float*)d_in[7];
  const float* Bg  = (const float*)d_in[8];
  const float* Uq  = (const float*)d_in[9];
  const float* UHq = (const float*)d_in[10];
  const float* Wq  = (const float*)d_in[11];
  const float* Bq  = (const float*)d_in[12];
  const float* Uc  = (const float*)d_in[13];
  const float* UHc = (const float*)d_in[14];
  const float* Wc  = (const float*)d_in[15];
  const float* Bc  = (const float*)d_in[16];
  float* out = (float*)d_out;

  float*    hbuf = (float*)d_ws;                      // [2][L][H] = 32 KB
  unsigned* prog = (unsigned*)((char*)d_ws + 2 * L * H * sizeof(float));  // 1 KB

  void* args[] = { (void*)&x,
                   (void*)&Uf, (void*)&Ug, (void*)&Uq, (void*)&Uc,
                   (void*)&UHf, (void*)&UHg, (void*)&UHq, (void*)&UHc,
                   (void*)&Wf, (void*)&Wg, (void*)&Wq, (void*)&Wc,
                   (void*)&Bf, (void*)&Bg, (void*)&Bq, (void*)&Bc,
                   (void*)&hbuf, (void*)&prog, (void*)&out };
  hipLaunchCooperativeKernel(reinterpret_cast<void*>(lstm_seq),
                             dim3(NWG), dim3(NTH), args, 0, stream);
}

// Round 6
// 40412.186 us; speedup vs baseline: 5.3646x; 2.3251x over previous
//
#include <hip/hip_runtime.h>
#include <hip/hip_cooperative_groups.h>
#include <cmath>

namespace cg = cooperative_groups;

#define TSEQ 2048
#define H    1024
#define L    4
#define WPL  64          // workgroups per layer
#define NWG  (WPL * L)   // 256 blocks = 1 per CU
#define NTH  512         // 8 waves per block

__device__ __forceinline__ float waveSum(float v) {
#pragma unroll
  for (int off = 32; off > 0; off >>= 1) v += __shfl_xor(v, off, 64);
  return v;
}

__device__ __forceinline__ float sigmoidf_(float x) {
  return 1.0f / (1.0f + __expf(-x));
}

__device__ __forceinline__ unsigned bf16rne(float f) {
  unsigned u = __float_as_uint(f);
  return (u + 0x7fffu + ((u >> 16) & 1u)) >> 16;
}

__device__ __forceinline__ unsigned ldAgent(const unsigned* p) {
  return __hip_atomic_load(p, __ATOMIC_RELAXED, __HIP_MEMORY_SCOPE_AGENT);
}
__device__ __forceinline__ void stAgentF(float* p, float v) {
  __hip_atomic_store(p, v, __ATOMIC_RELAXED, __HIP_MEMORY_SCOPE_AGENT);
}
__device__ __forceinline__ void stAgentU(unsigned* p, unsigned v) {
  __hip_atomic_store(p, v, __ATOMIC_RELAXED, __HIP_MEMORY_SCOPE_AGENT);
}
// 16 floats via 8 agent-scope b64 atomic loads (bypass L1/L2 -> always fresh)
__device__ __forceinline__ void ldh16(const float* p, float* dst) {
#pragma unroll
  for (int q = 0; q < 8; ++q) {
    unsigned long long v = __hip_atomic_load(
        (const unsigned long long*)p + q, __ATOMIC_RELAXED,
        __HIP_MEMORY_SCOPE_AGENT);
    dst[2 * q]     = __uint_as_float((unsigned)v);
    dst[2 * q + 1] = __uint_as_float((unsigned)(v >> 32));
  }
}

// Persistent-register-weight LSTM, dataflow sync, NO cache-wide fences in the
// hot loop: all cross-block data (h, prog) moves via agent-scope atomic
// stores/loads which are individually coherent at the MALL. Ordering:
// __syncthreads() drains vmcnt(0) per wave, so h stores are complete before
// tid0 publishes prog; consumers issue h loads only after observing prog.
// NOTE: hbuf/prog are NEVER touched by ordinary stores (incl. zero-init) so
// no stale dirty L2 line can ever write back over a newer MALL value.
__global__ __launch_bounds__(NTH, 2) void lstm_seq(
    const float* __restrict__ X,                                   // [TSEQ][H]
    const float* __restrict__ Uf,  const float* __restrict__ Ug,   // [H][H]
    const float* __restrict__ Uq,  const float* __restrict__ Uc,
    const float* __restrict__ UHf, const float* __restrict__ UHg,  // [L-1][H][H]
    const float* __restrict__ UHq, const float* __restrict__ UHc,
    const float* __restrict__ Wf,  const float* __restrict__ Wg,   // [L][H][H]
    const float* __restrict__ Wq,  const float* __restrict__ Wc,
    const float* __restrict__ Bf,  const float* __restrict__ Bg,   // [L][H]
    const float* __restrict__ Bq,  const float* __restrict__ Bc,
    float* __restrict__ hbuf,     // ws: [2][L][H] double-buffered hidden state
    unsigned* __restrict__ prog,  // ws: [L][WPL] progress slots
    float* __restrict__ out)      // [L][H]
{
  cg::grid_group grid = cg::this_grid();
  const int tid  = threadIdx.x;
  const int lane = tid & 63;
  const int wv   = tid >> 6;            // wave 0..7
  const int l    = blockIdx.x >> 6;     // layer 0..3
  const int wgl  = blockIdx.x & 63;     // block index within layer
  const int r0   = wgl * 16 + wv * 2;   // this wave's 2 output rows
  const int colBase = lane * 16;        // this lane's 16 contiguous columns

  // d_ws is poisoned 0xAA before every timed call: zero h state + slots.
  // MUST be atomic (write-through) stores -- see kernel comment.
  {
    const int gtid = blockIdx.x * NTH + tid;
    for (int i = gtid; i < 2 * L * H; i += NWG * NTH) stAgentF(&hbuf[i], 0.0f);
    for (int i = gtid; i < L * WPL; i += NWG * NTH) stAgentU(&prog[i], 0u);
  }

  // ---- matrix pointers: 0..3 = W-side (recurrent), 4..7 = U-side ----------
  const size_t lHH = (size_t)l * H * H;
  const float* Mp[8];
  Mp[0] = Wf + lHH; Mp[1] = Wg + lHH; Mp[2] = Wq + lHH; Mp[3] = Wc + lHH;
  if (l == 0) {
    Mp[4] = Uf; Mp[5] = Ug; Mp[6] = Uq; Mp[7] = Uc;
  } else {
    const size_t o = (size_t)(l - 1) * H * H;
    Mp[4] = UHf + o; Mp[5] = UHg + o; Mp[6] = UHq + o; Mp[7] = UHc + o;
  }

  // ---- one-time weight fetch -> bf16x2 packed registers (128 regs) --------
  unsigned wpk[8][2][8];
#pragma unroll
  for (int mi = 0; mi < 8; ++mi)
#pragma unroll
    for (int ri = 0; ri < 2; ++ri) {
      const float* rowp = Mp[mi] + (size_t)(r0 + ri) * H + colBase;
#pragma unroll
      for (int q = 0; q < 4; ++q) {
        float4 w4 = *(const float4*)(rowp + 4 * q);
        wpk[mi][ri][2 * q]     = bf16rne(w4.x) | (bf16rne(w4.y) << 16);
        wpk[mi][ri][2 * q + 1] = bf16rne(w4.z) | (bf16rne(w4.w) << 16);
      }
    }

  float bias[4][2];
#pragma unroll
  for (int ri = 0; ri < 2; ++ri) {
    bias[0][ri] = Bf[(size_t)l * H + r0 + ri];
    bias[1][ri] = Bg[(size_t)l * H + r0 + ri];
    bias[2][ri] = Bq[(size_t)l * H + r0 + ri];
    bias[3][ri] = Bc[(size_t)l * H + r0 + ri];
  }

  float sreg[2] = {0.0f, 0.0f};  // cell state for this wave's 2 rows

  __threadfence();
  grid.sync();   // one-time: init visible everywhere

  for (int t = 0; t < TSEQ; ++t) {
    // ---- dataflow gate: wave 0 spins lane-parallel on progress slots ------
    if (wv == 0) {
      for (;;) {
        bool c = true;
        if (t > 0)
          c = (ldAgent(&prog[l * WPL + lane]) >= (unsigned)t);
        if (l > 0)
          c = c && (ldAgent(&prog[(l - 1) * WPL + lane]) >= (unsigned)(t + 1));
        if (l < L - 1 && t >= 2)
          c = c && (ldAgent(&prog[(l + 1) * WPL + lane]) >= (unsigned)(t - 1));
        if (__all(c)) break;
        __builtin_amdgcn_s_sleep(1);
      }
    }
    __syncthreads();
    __builtin_amdgcn_sched_barrier(0);  // keep h loads after the gate

    const float* hprev = hbuf + ((size_t)((t - 1) & 1) * L + l) * H + colBase;

    float ha[16], hb[16];
    ldh16(hprev, ha);
    if (l == 0) {
      const float* xin = X + (size_t)t * H + colBase;
#pragma unroll
      for (int q = 0; q < 4; ++q) {
        float4 b4 = *(const float4*)(xin + 4 * q);
        hb[4 * q] = b4.x; hb[4 * q + 1] = b4.y;
        hb[4 * q + 2] = b4.z; hb[4 * q + 3] = b4.w;
      }
    } else {
      ldh16(hbuf + ((size_t)(t & 1) * L + (l - 1)) * H + colBase, hb);
    }

    float acc[4][2];
#pragma unroll
    for (int g = 0; g < 4; ++g)
#pragma unroll
      for (int ri = 0; ri < 2; ++ri) {
        float a = 0.0f;
#pragma unroll
        for (int jj = 0; jj < 8; ++jj) {
          const unsigned wA = wpk[g][ri][jj];        // W-side (recurrent)
          a = fmaf(__uint_as_float(wA << 16),         ha[2 * jj],     a);
          a = fmaf(__uint_as_float(wA & 0xffff0000u), ha[2 * jj + 1], a);
          const unsigned wB = wpk[4 + g][ri][jj];    // U-side (input/below)
          a = fmaf(__uint_as_float(wB << 16),         hb[2 * jj],     a);
          a = fmaf(__uint_as_float(wB & 0xffff0000u), hb[2 * jj + 1], a);
        }
        acc[g][ri] = a;
      }

#pragma unroll
    for (int g = 0; g < 4; ++g)
#pragma unroll
      for (int ri = 0; ri < 2; ++ri) acc[g][ri] = waveSum(acc[g][ri]);

#pragma unroll
    for (int ri = 0; ri < 2; ++ri) {
      float f  = sigmoidf_(bias[0][ri] + acc[0][ri]);
      float g_ = sigmoidf_(bias[1][ri] + acc[1][ri]);
      float q_ = sigmoidf_(bias[2][ri] + acc[2][ri]);
      float cd = sigmoidf_(bias[3][ri] + acc[3][ri]);
      float sN = f * sreg[ri] + g_ * cd;
      sreg[ri] = sN;
      float hN = tanhf(sN) * q_;
      if (lane == ri) {
        stAgentF(&hbuf[((size_t)(t & 1) * L + l) * H + r0 + ri], hN);
        if (t == TSEQ - 1) out[(size_t)l * H + r0 + ri] = hN;
      }
    }

    // __syncthreads drains vmcnt(0) per wave before the barrier -> all h
    // atomic stores of this block have landed at the coherence point.
    __syncthreads();
    if (tid == 0)
      stAgentU(&prog[l * WPL + wgl], (unsigned)(t + 1));
  }
}

// ---------------- launch ----------------------------------------------------
extern "C" void kernel_launch(void* const* d_in, const int* in_sizes, int n_in,
                              void* d_out, int out_size, void* d_ws, size_t ws_size,
                              hipStream_t stream) {
  const float* x   = (const float*)d_in[0];
  const float* Uf  = (const float*)d_in[1];
  const float* UHf = (const float*)d_in[2];
  const float* Wf  = (const float*)d_in[3];
  const float* Bf  = (const float*)d_in[4];
  const float* Ug  = (const float*)d_in[5];
  const float* UHg = (const float*)d_in[6];
  const float* Wg  = (const float*)d_in[7];
  const float* Bg  = (const float*)d_in[8];
  const float* Uq  = (const float*)d_in[9];
  const float* UHq = (const float*)d_in[10];
  const float* Wq  = (const float*)d_in[11];
  const float* Bq  = (const float*)d_in[12];
  const float* Uc  = (const float*)d_in[13];
  const float* UHc = (const float*)d_in[14];
  const float* Wc  = (const float*)d_in[15];
  const float* Bc  = (const float*)d_in[16];
  float* out = (float*)d_out;

  float*    hbuf = (float*)d_ws;                      // [2][L][H] = 32 KB
  unsigned* prog = (unsigned*)((char*)d_ws + 2 * L * H * sizeof(float));  // 1 KB

  void* args[] = { (void*)&x,
                   (void*)&Uf, (void*)&Ug, (void*)&Uq, (void*)&Uc,
                   (void*)&UHf, (void*)&UHg, (void*)&UHq, (void*)&UHc,
                   (void*)&Wf, (void*)&Wg, (void*)&Wq, (void*)&Wc,
                   (void*)&Bf, (void*)&Bg, (void*)&Bq, (void*)&Bc,
                   (void*)&hbuf, (void*)&prog, (void*)&out };
  hipLaunchCooperativeKernel(reinterpret_cast<void*>(lstm_seq),
                             dim3(NWG), dim3(NTH), args, 0, stream);
}

// Round 7
// 34060.492 us; speedup vs baseline: 6.3650x; 1.1865x over previous
//
#include <hip/hip_runtime.h>
#include <hip/hip_cooperative_groups.h>
#include <cmath>

namespace cg = cooperative_groups;

#define TSEQ 2048
#define H    1024
#define L    4
#define WPL  64          // workgroups per layer
#define NWG  (WPL * L)   // 256 blocks = 1 per CU
#define NTH  512         // 8 waves per block

typedef unsigned u32;
typedef unsigned long long u64;

__device__ __forceinline__ float waveSum(float v) {
#pragma unroll
  for (int off = 32; off > 0; off >>= 1) v += __shfl_xor(v, off, 64);
  return v;
}

__device__ __forceinline__ float sigmoidf_(float x) {
  return 1.0f / (1.0f + __expf(-x));
}

__device__ __forceinline__ unsigned bf16rne(float f) {
  unsigned u = __float_as_uint(f);
  return (u + 0x7fffu + ((u >> 16) & 1u)) >> 16;
}

__device__ __forceinline__ u32 ldCnt(const u32* p) {
  return __hip_atomic_load(p, __ATOMIC_RELAXED, __HIP_MEMORY_SCOPE_AGENT);
}
__device__ __forceinline__ u64 ldU64(const u64* p) {
  return __hip_atomic_load(p, __ATOMIC_RELAXED, __HIP_MEMORY_SCOPE_AGENT);
}
__device__ __forceinline__ void stAgentF(float* p, float v) {
  __hip_atomic_store(p, v, __ATOMIC_RELAXED, __HIP_MEMORY_SCOPE_AGENT);
}
__device__ __forceinline__ void stAgentU(u32* p, u32 v) {
  __hip_atomic_store(p, v, __ATOMIC_RELAXED, __HIP_MEMORY_SCOPE_AGENT);
}

// Persistent-register-weight LSTM, dataflow sync via per-layer aggregate
// counters (atomicAdd), h broadcast staged through LDS.
//  - cnt[l] (own 64B line each) counts block-step completions of layer l.
//    Invariant: intra-layer skew <= 1 step  =>  cnt[l] >= 64*t  <=>  every
//    block of layer l has finished step t-1. Gates:
//      own   : cnt[l]   >= 64*t        (h_l(t-1) complete)
//      below : cnt[l-1] >= 64*(t+1)    (h_{l-1}(t) complete)       [l>0]
//      WAR   : cnt[l+1] >= 64*(t-1)    (h_l(t-2) consumed)         [l<L-1]
//    Poll = 3 lanes x 1 uncached dword (192B/iter) + s_sleep backoff, so
//    polling cannot saturate the coherent fabric (round-6 failure mode).
//  - h vectors are loaded from MALL once per block (512 x b64 agent loads)
//    into LDS; the 8 waves read their slices from LDS (was 8x global).
//  - hbuf/cnt are touched ONLY by agent-scope atomics (incl. zero-init) so
//    no stale dirty L2 line can write back over a newer MALL value.
// Lane column ownership is strided pairs: lane owns cols {2*lane+128q,+1},
// q=0..7 -> LDS b64 reads are conflict-free, weight fetch stays coalesced.
__global__ __launch_bounds__(NTH, 2) void lstm_seq(
    const float* __restrict__ X,                                   // [TSEQ][H]
    const float* __restrict__ Uf,  const float* __restrict__ Ug,   // [H][H]
    const float* __restrict__ Uq,  const float* __restrict__ Uc,
    const float* __restrict__ UHf, const float* __restrict__ UHg,  // [L-1][H][H]
    const float* __restrict__ UHq, const float* __restrict__ UHc,
    const float* __restrict__ Wf,  const float* __restrict__ Wg,   // [L][H][H]
    const float* __restrict__ Wq,  const float* __restrict__ Wc,
    const float* __restrict__ Bf,  const float* __restrict__ Bg,   // [L][H]
    const float* __restrict__ Bq,  const float* __restrict__ Bc,
    float* __restrict__ hbuf,   // ws: [2][L][H] double-buffered hidden state
    u32*   __restrict__ cnt,    // ws: [L][16] padded per-layer counters
    float* __restrict__ out)    // [L][H]
{
  cg::grid_group grid = cg::this_grid();
  const int tid  = threadIdx.x;
  const int lane = tid & 63;
  const int wv   = tid >> 6;            // wave 0..7
  const int l    = blockIdx.x >> 6;     // layer 0..3
  const int wgl  = blockIdx.x & 63;     // block index within layer
  const int r0   = wgl * 16 + wv * 2;   // this wave's 2 output rows

  // d_ws poisoned 0xAA before every call: zero h state + counters (atomics!)
  {
    const int gtid = blockIdx.x * NTH + tid;
    for (int i = gtid; i < 2 * L * H; i += NWG * NTH) stAgentF(&hbuf[i], 0.0f);
    for (int i = gtid; i < L * 16; i += NWG * NTH) stAgentU(&cnt[i], 0u);
  }

  // ---- matrix pointers: 0..3 = W-side (recurrent), 4..7 = U-side ----------
  const size_t lHH = (size_t)l * H * H;
  const float* Mp[8];
  Mp[0] = Wf + lHH; Mp[1] = Wg + lHH; Mp[2] = Wq + lHH; Mp[3] = Wc + lHH;
  if (l == 0) {
    Mp[4] = Uf; Mp[5] = Ug; Mp[6] = Uq; Mp[7] = Uc;
  } else {
    const size_t o = (size_t)(l - 1) * H * H;
    Mp[4] = UHf + o; Mp[5] = UHg + o; Mp[6] = UHq + o; Mp[7] = UHc + o;
  }

  // ---- one-time weight fetch -> bf16x2 packed registers (128 regs) --------
  // wpk[mi][ri][q] holds cols {2*lane+128q (lo), +1 (hi)} of row r0+ri.
  unsigned wpk[8][2][8];
#pragma unroll
  for (int mi = 0; mi < 8; ++mi)
#pragma unroll
    for (int ri = 0; ri < 2; ++ri) {
      const float* rowp = Mp[mi] + (size_t)(r0 + ri) * H + 2 * lane;
#pragma unroll
      for (int q = 0; q < 8; ++q) {
        float2 w2 = *(const float2*)(rowp + 128 * q);
        wpk[mi][ri][q] = bf16rne(w2.x) | (bf16rne(w2.y) << 16);
      }
    }

  float bias[4][2];
#pragma unroll
  for (int ri = 0; ri < 2; ++ri) {
    bias[0][ri] = Bf[(size_t)l * H + r0 + ri];
    bias[1][ri] = Bg[(size_t)l * H + r0 + ri];
    bias[2][ri] = Bq[(size_t)l * H + r0 + ri];
    bias[3][ri] = Bq == Bc ? 0.0f : Bc[(size_t)l * H + r0 + ri];
  }

  float sreg[2] = {0.0f, 0.0f};  // cell state for this wave's 2 rows

  __shared__ float hAsh[H];  // own h(t-1)
  __shared__ float hBsh[H];  // layer-0: x_t ; layers 1-3: h_below(t)

  __threadfence();
  grid.sync();   // one-time: init visible everywhere

  for (int t = 0; t < TSEQ; ++t) {
    // ---- dataflow gate: wave 0, 3 lanes poll 3 counters ------------------
    if (wv == 0) {
      for (;;) {
        bool c = true;
        if (lane == 0) {
          if (t > 0) c = (ldCnt(&cnt[l * 16]) >= 64u * (u32)t);
        } else if (lane == 1) {
          if (l > 0) c = (ldCnt(&cnt[(l - 1) * 16]) >= 64u * (u32)(t + 1));
        } else if (lane == 2) {
          if (l < L - 1 && t >= 2)
            c = (ldCnt(&cnt[(l + 1) * 16]) >= 64u * (u32)(t - 1));
        }
        if (__all(c)) break;
        __builtin_amdgcn_s_sleep(2);
      }
    }
    __syncthreads();

    // ---- stage h vectors into LDS (once per block) -----------------------
    {
      const float* srcA = hbuf + ((size_t)((t - 1) & 1) * L + l) * H;
      u64 va = ldU64((const u64*)srcA + tid);
      ((u64*)hAsh)[tid] = va;
      if (l == 0) {
        float2 xb = *(const float2*)(X + (size_t)t * H + 2 * tid);
        hBsh[2 * tid] = xb.x; hBsh[2 * tid + 1] = xb.y;
      } else {
        const float* srcB = hbuf + ((size_t)(t & 1) * L + (l - 1)) * H;
        u64 vb = ldU64((const u64*)srcB + tid);
        ((u64*)hBsh)[tid] = vb;
      }
    }
    __syncthreads();

    // ---- per-lane slices from LDS (conflict-free b64 pattern) ------------
    float ha[16], hb[16];
#pragma unroll
    for (int q = 0; q < 8; ++q) {
      u64 va = ((const u64*)hAsh)[lane + 64 * q];
      ha[2 * q]     = __uint_as_float((u32)va);
      ha[2 * q + 1] = __uint_as_float((u32)(va >> 32));
      u64 vb = ((const u64*)hBsh)[lane + 64 * q];
      hb[2 * q]     = __uint_as_float((u32)vb);
      hb[2 * q + 1] = __uint_as_float((u32)(vb >> 32));
    }

    float acc[4][2];
#pragma unroll
    for (int g = 0; g < 4; ++g)
#pragma unroll
      for (int ri = 0; ri < 2; ++ri) {
        float a = 0.0f;
#pragma unroll
        for (int q = 0; q < 8; ++q) {
          const unsigned wA = wpk[g][ri][q];         // W-side (recurrent)
          a = fmaf(__uint_as_float(wA << 16),         ha[2 * q],     a);
          a = fmaf(__uint_as_float(wA & 0xffff0000u), ha[2 * q + 1], a);
          const unsigned wB = wpk[4 + g][ri][q];     // U-side (input/below)
          a = fmaf(__uint_as_float(wB << 16),         hb[2 * q],     a);
          a = fmaf(__uint_as_float(wB & 0xffff0000u), hb[2 * q + 1], a);
        }
        acc[g][ri] = a;
      }

#pragma unroll
    for (int g = 0; g < 4; ++g)
#pragma unroll
      for (int ri = 0; ri < 2; ++ri) acc[g][ri] = waveSum(acc[g][ri]);

#pragma unroll
    for (int ri = 0; ri < 2; ++ri) {
      float f  = sigmoidf_(bias[0][ri] + acc[0][ri]);
      float g_ = sigmoidf_(bias[1][ri] + acc[1][ri]);
      float q_ = sigmoidf_(bias[2][ri] + acc[2][ri]);
      float cd = sigmoidf_(bias[3][ri] + acc[3][ri]);
      float sN = f * sreg[ri] + g_ * cd;
      sreg[ri] = sN;
      float hN = tanhf(sN) * q_;
      if (lane == ri) {
        stAgentF(&hbuf[((size_t)(t & 1) * L + l) * H + r0 + ri], hN);
        if (t == TSEQ - 1) out[(size_t)l * H + r0 + ri] = hN;
      }
    }

    // __syncthreads drains vmcnt(0) per wave -> this block's h stores have
    // all landed at the coherence point before tid0 publishes.
    __syncthreads();
    if (tid == 0)
      __hip_atomic_fetch_add(&cnt[l * 16], 1u,
                             __ATOMIC_RELAXED, __HIP_MEMORY_SCOPE_AGENT);
  }
}

// ---------------- launch ----------------------------------------------------
extern "C" void kernel_launch(void* const* d_in, const int* in_sizes, int n_in,
                              void* d_out, int out_size, void* d_ws, size_t ws_size,
                              hipStream_t stream) {
  const float* x   = (const float*)d_in[0];
  const float* Uf  = (const float*)d_in[1];
  const float* UHf = (const float*)d_in[2];
  const float* Wf  = (const float*)d_in[3];
  const float* Bf  = (const float*)d_in[4];
  const float* Ug  = (const float*)d_in[5];
  const float* UHg = (const float*)d_in[6];
  const float* Wg  = (const float*)d_in[7];
  const float* Bg  = (const float*)d_in[8];
  const float* Uq  = (const float*)d_in[9];
  const float* UHq = (const float*)d_in[10];
  const float* Wq  = (const float*)d_in[11];
  const float* Bq  = (const float*)d_in[12];
  const float* Uc  = (const float*)d_in[13];
  const float* UHc = (const float*)d_in[14];
  const float* Wc  = (const float*)d_in[15];
  const float* Bc  = (const float*)d_in[16];
  float* out = (float*)d_out;

  float* hbuf = (float*)d_ws;                                  // 32 KB
  u32*   cnt  = (u32*)((char*)d_ws + 2 * L * H * sizeof(float)); // 256 B

  void* args[] = { (void*)&x,
                   (void*)&Uf, (void*)&Ug, (void*)&Uq, (void*)&Uc,
                   (void*)&UHf, (void*)&UHg, (void*)&UHq, (void*)&UHc,
                   (void*)&Wf, (void*)&Wg, (void*)&Wq, (void*)&Wc,
                   (void*)&Bf, (void*)&Bg, (void*)&Bq, (void*)&Bc,
                   (void*)&hbuf, (void*)&cnt, (void*)&out };
  hipLaunchCooperativeKernel(reinterpret_cast<void*>(lstm_seq),
                             dim3(NWG), dim3(NTH), args, 0, stream);
}

// Round 8
// 28984.167 us; speedup vs baseline: 7.4797x; 1.1751x over previous
//
#include <hip/hip_runtime.h>
#include <hip/hip_cooperative_groups.h>
#include <cmath>

namespace cg = cooperative_groups;

#define TSEQ 2048
#define H    1024
#define L    4
#define WPL  64          // workgroups per layer
#define NWG  (WPL * L)   // 256 blocks = 1 per CU
#define NTH  512         // 8 waves per block
#define MBS  192         // mailbox slots/block: [0,64)=own, [64,128)=below, [128,192)=WAR

typedef unsigned u32;
typedef unsigned long long u64;

__device__ __forceinline__ float waveSum(float v) {
#pragma unroll
  for (int off = 32; off > 0; off >>= 1) v += __shfl_xor(v, off, 64);
  return v;
}

__device__ __forceinline__ float sigmoidf_(float x) {
  return 1.0f / (1.0f + __expf(-x));
}

__device__ __forceinline__ unsigned bf16rne(float f) {
  unsigned u = __float_as_uint(f);
  return (u + 0x7fffu + ((u >> 16) & 1u)) >> 16;
}

__device__ __forceinline__ u32 ldAgent(const u32* p) {
  return __hip_atomic_load(p, __ATOMIC_RELAXED, __HIP_MEMORY_SCOPE_AGENT);
}
__device__ __forceinline__ u64 ldU64(const u64* p) {
  return __hip_atomic_load(p, __ATOMIC_RELAXED, __HIP_MEMORY_SCOPE_AGENT);
}
__device__ __forceinline__ void stAgentF(float* p, float v) {
  __hip_atomic_store(p, v, __ATOMIC_RELAXED, __HIP_MEMORY_SCOPE_AGENT);
}
__device__ __forceinline__ void stAgentU(u32* p, u32 v) {
  __hip_atomic_store(p, v, __ATOMIC_RELAXED, __HIP_MEMORY_SCOPE_AGENT);
}

// Persistent-register-weight LSTM; dataflow sync via PER-CONSUMER MAILBOXES
// (push notification). Round-7 lesson: shared per-layer counters concentrate
// ~192 pollers on one MALL line; same-line service queueing (~30-40ns/req)
// made each publish->observe hop ~7us. Here:
//  - mbox[b][s]: consumer block b polls ONLY its own 192 slots (own-layer
//    stamps [0,64), below-layer [64,128), WAR/above [128,192)). Per-line
//    pollers = 16 lanes of ONE block -> no cross-block read contention.
//  - Producer (l,j) after vmcnt-drain (__syncthreads) pushes stamp t+1 into
//    the 192 consumers that need it (3 scattered 4B agent stores per wave-0
//    lane). Fire-and-forget, no RMW, no hot line.
// Gate semantics (unchanged, proven r5-r7):
//   own  : all layer-l blocks finished step t-1   (stamp >= t)
//   below: all layer-(l-1) blocks finished step t (stamp >= t+1)   [l>0]
//   WAR  : all layer-(l+1) blocks finished t-2    (stamp >= t-1)   [l<L-1, t>=2]
// hbuf/mbox touched ONLY by agent-scope atomics (incl. zero-init) so no
// stale dirty L2 line can write back over a newer MALL value.
__global__ __launch_bounds__(NTH, 2) void lstm_seq(
    const float* __restrict__ X,                                   // [TSEQ][H]
    const float* __restrict__ Uf,  const float* __restrict__ Ug,   // [H][H]
    const float* __restrict__ Uq,  const float* __restrict__ Uc,
    const float* __restrict__ UHf, const float* __restrict__ UHg,  // [L-1][H][H]
    const float* __restrict__ UHq, const float* __restrict__ UHc,
    const float* __restrict__ Wf,  const float* __restrict__ Wg,   // [L][H][H]
    const float* __restrict__ Wq,  const float* __restrict__ Wc,
    const float* __restrict__ Bf,  const float* __restrict__ Bg,   // [L][H]
    const float* __restrict__ Bq,  const float* __restrict__ Bc,
    float* __restrict__ hbuf,   // ws: [2][L][H] double-buffered hidden state
    u32*   __restrict__ mbox,   // ws: [NWG][MBS] per-consumer stamp slots
    float* __restrict__ out)    // [L][H]
{
  cg::grid_group grid = cg::this_grid();
  const int tid  = threadIdx.x;
  const int lane = tid & 63;
  const int wv   = tid >> 6;            // wave 0..7
  const int l    = blockIdx.x >> 6;     // layer 0..3
  const int wgl  = blockIdx.x & 63;     // block index within layer
  const int r0   = wgl * 16 + wv * 2;   // this wave's 2 output rows

  // d_ws poisoned 0xAA before every call: zero h state + mailboxes (atomics!)
  {
    const int gtid = blockIdx.x * NTH + tid;
    for (int i = gtid; i < 2 * L * H; i += NWG * NTH) stAgentF(&hbuf[i], 0.0f);
    for (int i = gtid; i < NWG * MBS; i += NWG * NTH) stAgentU(&mbox[i], 0u);
  }

  // ---- matrix pointers: 0..3 = W-side (recurrent), 4..7 = U-side ----------
  const size_t lHH = (size_t)l * H * H;
  const float* Mp[8];
  Mp[0] = Wf + lHH; Mp[1] = Wg + lHH; Mp[2] = Wq + lHH; Mp[3] = Wc + lHH;
  if (l == 0) {
    Mp[4] = Uf; Mp[5] = Ug; Mp[6] = Uq; Mp[7] = Uc;
  } else {
    const size_t o = (size_t)(l - 1) * H * H;
    Mp[4] = UHf + o; Mp[5] = UHg + o; Mp[6] = UHq + o; Mp[7] = UHc + o;
  }

  // ---- one-time weight fetch -> bf16x2 packed registers (128 regs) --------
  // wpk[mi][ri][q] holds cols {2*lane+128q (lo), +1 (hi)} of row r0+ri.
  unsigned wpk[8][2][8];
#pragma unroll
  for (int mi = 0; mi < 8; ++mi)
#pragma unroll
    for (int ri = 0; ri < 2; ++ri) {
      const float* rowp = Mp[mi] + (size_t)(r0 + ri) * H + 2 * lane;
#pragma unroll
      for (int q = 0; q < 8; ++q) {
        float2 w2 = *(const float2*)(rowp + 128 * q);
        wpk[mi][ri][q] = bf16rne(w2.x) | (bf16rne(w2.y) << 16);
      }
    }

  float bias[4][2];
#pragma unroll
  for (int ri = 0; ri < 2; ++ri) {
    bias[0][ri] = Bf[(size_t)l * H + r0 + ri];
    bias[1][ri] = Bg[(size_t)l * H + r0 + ri];
    bias[2][ri] = Bq[(size_t)l * H + r0 + ri];
    bias[3][ri] = Bc[(size_t)l * H + r0 + ri];
  }

  float sreg[2] = {0.0f, 0.0f};  // cell state for this wave's 2 rows

  __shared__ float hAsh[H];  // own h(t-1)
  __shared__ float hBsh[H];  // layer-0: x_t ; layers 1-3: h_below(t)

  __threadfence();
  grid.sync();   // one-time: init visible everywhere

  const u32* mb = mbox + (size_t)blockIdx.x * MBS;

  for (int t = 0; t < TSEQ; ++t) {
    const u32 tu = (u32)t;
    // ---- dataflow gate: wave 0 polls ITS OWN mailbox slots ---------------
    if (wv == 0) {
      for (;;) {
        bool c = true;
        if (t > 0)               c =      (ldAgent(&mb[lane])       >= tu);
        if (l > 0)               c = c && (ldAgent(&mb[64 + lane])  >= tu + 1);
        if (l < L - 1 && t >= 2) c = c && (ldAgent(&mb[128 + lane]) >= tu - 1);
        if (__all(c)) break;
        __builtin_amdgcn_s_sleep(2);
      }
    }
    __syncthreads();

    // ---- stage h vectors into LDS (once per block) -----------------------
    {
      const float* srcA = hbuf + ((size_t)((t - 1) & 1) * L + l) * H;
      u64 va = ldU64((const u64*)srcA + tid);
      ((u64*)hAsh)[tid] = va;
      if (l == 0) {
        float2 xb = *(const float2*)(X + (size_t)t * H + 2 * tid);
        hBsh[2 * tid] = xb.x; hBsh[2 * tid + 1] = xb.y;
      } else {
        const float* srcB = hbuf + ((size_t)(t & 1) * L + (l - 1)) * H;
        u64 vb = ldU64((const u64*)srcB + tid);
        ((u64*)hBsh)[tid] = vb;
      }
    }
    __syncthreads();

    // ---- per-lane slices from LDS (conflict-free b64 pattern) ------------
    float ha[16], hb[16];
#pragma unroll
    for (int q = 0; q < 8; ++q) {
      u64 va = ((const u64*)hAsh)[lane + 64 * q];
      ha[2 * q]     = __uint_as_float((u32)va);
      ha[2 * q + 1] = __uint_as_float((u32)(va >> 32));
      u64 vb = ((const u64*)hBsh)[lane + 64 * q];
      hb[2 * q]     = __uint_as_float((u32)vb);
      hb[2 * q + 1] = __uint_as_float((u32)(vb >> 32));
    }

    float acc[4][2];
#pragma unroll
    for (int g = 0; g < 4; ++g)
#pragma unroll
      for (int ri = 0; ri < 2; ++ri) {
        float a = 0.0f;
#pragma unroll
        for (int q = 0; q < 8; ++q) {
          const unsigned wA = wpk[g][ri][q];         // W-side (recurrent)
          a = fmaf(__uint_as_float(wA << 16),         ha[2 * q],     a);
          a = fmaf(__uint_as_float(wA & 0xffff0000u), ha[2 * q + 1], a);
          const unsigned wB = wpk[4 + g][ri][q];     // U-side (input/below)
          a = fmaf(__uint_as_float(wB << 16),         hb[2 * q],     a);
          a = fmaf(__uint_as_float(wB & 0xffff0000u), hb[2 * q + 1], a);
        }
        acc[g][ri] = a;
      }

#pragma unroll
    for (int g = 0; g < 4; ++g)
#pragma unroll
      for (int ri = 0; ri < 2; ++ri) acc[g][ri] = waveSum(acc[g][ri]);

#pragma unroll
    for (int ri = 0; ri < 2; ++ri) {
      float f  = sigmoidf_(bias[0][ri] + acc[0][ri]);
      float g_ = sigmoidf_(bias[1][ri] + acc[1][ri]);
      float q_ = sigmoidf_(bias[2][ri] + acc[2][ri]);
      float cd = sigmoidf_(bias[3][ri] + acc[3][ri]);
      float sN = f * sreg[ri] + g_ * cd;
      sreg[ri] = sN;
      float hN = tanhf(sN) * q_;
      if (lane == ri) {
        stAgentF(&hbuf[((size_t)(t & 1) * L + l) * H + r0 + ri], hN);
        if (t == TSEQ - 1) out[(size_t)l * H + r0 + ri] = hN;
      }
    }

    // __syncthreads drains vmcnt per wave -> this block's h stores have all
    // landed at the coherence point; then wave 0 pushes notifications.
    __syncthreads();
    if (wv == 0) {
      const u32 v = tu + 1;
      // own-layer consumers (their slot [wgl] in region 0)
      stAgentU(mbox + (size_t)(l * WPL + lane) * MBS + wgl, v);
      // above-layer consumers' "below" region
      if (l < L - 1)
        stAgentU(mbox + (size_t)((l + 1) * WPL + lane) * MBS + 64 + wgl, v);
      // below-layer consumers' "WAR" region
      if (l > 0)
        stAgentU(mbox + (size_t)((l - 1) * WPL + lane) * MBS + 128 + wgl, v);
    }
  }
}

// ---------------- launch ----------------------------------------------------
extern "C" void kernel_launch(void* const* d_in, const int* in_sizes, int n_in,
                              void* d_out, int out_size, void* d_ws, size_t ws_size,
                              hipStream_t stream) {
  const float* x   = (const float*)d_in[0];
  const float* Uf  = (const float*)d_in[1];
  const float* UHf = (const float*)d_in[2];
  const float* Wf  = (const float*)d_in[3];
  const float* Bf  = (const float*)d_in[4];
  const float* Ug  = (const float*)d_in[5];
  const float* UHg = (const float*)d_in[6];
  const float* Wg  = (const float*)d_in[7];
  const float* Bg  = (const float*)d_in[8];
  const float* Uq  = (const float*)d_in[9];
  const float* UHq = (const float*)d_in[10];
  const float* Wq  = (const float*)d_in[11];
  const float* Bq  = (const float*)d_in[12];
  const float* Uc  = (const float*)d_in[13];
  const float* UHc = (const float*)d_in[14];
  const float* Wc  = (const float*)d_in[15];
  const float* Bc  = (const float*)d_in[16];
  float* out = (float*)d_out;

  float* hbuf = (float*)d_ws;                                    // 32 KB
  u32*   mbox = (u32*)((char*)d_ws + 2 * L * H * sizeof(float)); // 192 KB

  void* args[] = { (void*)&x,
                   (void*)&Uf, (void*)&Ug, (void*)&Uq, (void*)&Uc,
                   (void*)&UHf, (void*)&UHg, (void*)&UHq, (void*)&UHc,
                   (void*)&Wf, (void*)&Wg, (void*)&Wq, (void*)&Wc,
                   (void*)&Bf, (void*)&Bg, (void*)&Bq, (void*)&Bc,
                   (void*)&hbuf, (void*)&mbox, (void*)&out };
  hipLaunchCooperativeKernel(reinterpret_cast<void*>(lstm_seq),
                             dim3(NWG), dim3(NTH), args, 0, stream);
}

// Round 9
// 21190.428 us; speedup vs baseline: 10.2308x; 1.3678x over previous
//
#include <hip/hip_runtime.h>
#include <hip/hip_cooperative_groups.h>
#include <cmath>

namespace cg = cooperative_groups;

#define TSEQ 2048
#define H    1024
#define L    4
#define WPL  64          // workgroups per layer
#define NWG  (WPL * L)   // 256 blocks = 1 per CU
#define NTH  512         // 8 waves per block
#define MBS  192         // mailbox slots/block: [0,64)=own, [64,128)=below, [128,192)=WAR
#define NBUF 4           // h ring depth (power of 2)

typedef unsigned u32;
typedef unsigned long long u64;

__device__ __forceinline__ float waveSum(float v) {
#pragma unroll
  for (int off = 32; off > 0; off >>= 1) v += __shfl_xor(v, off, 64);
  return v;
}

__device__ __forceinline__ float sigmoidf_(float x) {
  return 1.0f / (1.0f + __expf(-x));
}

__device__ __forceinline__ unsigned bf16rne(float f) {
  unsigned u = __float_as_uint(f);
  return (u + 0x7fffu + ((u >> 16) & 1u)) >> 16;
}

__device__ __forceinline__ u32 ldAgent(const u32* p) {
  return __hip_atomic_load(p, __ATOMIC_RELAXED, __HIP_MEMORY_SCOPE_AGENT);
}
__device__ __forceinline__ void stAgentF(float* p, float v) {
  __hip_atomic_store(p, v, __ATOMIC_RELAXED, __HIP_MEMORY_SCOPE_AGENT);
}
__device__ __forceinline__ void stAgentU(u32* p, u32 v) {
  __hip_atomic_store(p, v, __ATOMIC_RELAXED, __HIP_MEMORY_SCOPE_AGENT);
}
__device__ __forceinline__ void stAgentU64(u64* p, u64 v) {
  __hip_atomic_store(p, v, __ATOMIC_RELAXED, __HIP_MEMORY_SCOPE_AGENT);
}
// Coalesced 16B load that bypasses L1/L2 (served at the coherence point):
// plain load + sc0 sc1 -> fresh data like an atomic, but coalesces normally.
__device__ __forceinline__ float4 ldBypass16(const float* p) {
  float4 r;
  asm volatile("global_load_dwordx4 %0, %1, off sc0 sc1\n\t"
               "s_waitcnt vmcnt(0)"
               : "=v"(r) : "v"(p) : "memory");
  return r;
}

// Persistent-register-weight LSTM; per-consumer mailbox dataflow sync
// (round 8) + this round: coalesced bypass h-loads, packed h-stores,
// 4-deep h ring to decouple WAR by 3 steps.
// Gates for block (l,*) at step t (stamps in own mailbox):
//   own  : all layer-l     blocks finished t-1  (stamp >= t)     [t>0]
//   below: all layer-(l-1) blocks finished t    (stamp >= t+1)   [l>0]
//   WAR  : all layer-(l+1) blocks finished t-3  (stamp >= t-3)   [l<L-1, t>=4]
// hbuf/mbox are written ONLY via agent-scope atomics; read via atomics or
// sc0/sc1 bypass loads -> no stale L2 lines can exist for these buffers.
__global__ __launch_bounds__(NTH, 2) void lstm_seq(
    const float* __restrict__ X,                                   // [TSEQ][H]
    const float* __restrict__ Uf,  const float* __restrict__ Ug,   // [H][H]
    const float* __restrict__ Uq,  const float* __restrict__ Uc,
    const float* __restrict__ UHf, const float* __restrict__ UHg,  // [L-1][H][H]
    const float* __restrict__ UHq, const float* __restrict__ UHc,
    const float* __restrict__ Wf,  const float* __restrict__ Wg,   // [L][H][H]
    const float* __restrict__ Wq,  const float* __restrict__ Wc,
    const float* __restrict__ Bf,  const float* __restrict__ Bg,   // [L][H]
    const float* __restrict__ Bq,  const float* __restrict__ Bc,
    float* __restrict__ hbuf,   // ws: [NBUF][L][H] h ring buffer
    u32*   __restrict__ mbox,   // ws: [NWG][MBS] per-consumer stamp slots
    float* __restrict__ out)    // [L][H]
{
  cg::grid_group grid = cg::this_grid();
  const int tid  = threadIdx.x;
  const int lane = tid & 63;
  const int wv   = tid >> 6;            // wave 0..7
  const int l    = blockIdx.x >> 6;     // layer 0..3
  const int wgl  = blockIdx.x & 63;     // block index within layer
  const int r0   = wgl * 16 + wv * 2;   // this wave's 2 output rows

  // d_ws poisoned 0xAA before every call: zero h ring + mailboxes (atomics!)
  {
    const int gtid = blockIdx.x * NTH + tid;
    for (int i = gtid; i < NBUF * L * H; i += NWG * NTH) stAgentF(&hbuf[i], 0.0f);
    for (int i = gtid; i < NWG * MBS; i += NWG * NTH) stAgentU(&mbox[i], 0u);
  }

  // ---- matrix pointers: 0..3 = W-side (recurrent), 4..7 = U-side ----------
  const size_t lHH = (size_t)l * H * H;
  const float* Mp[8];
  Mp[0] = Wf + lHH; Mp[1] = Wg + lHH; Mp[2] = Wq + lHH; Mp[3] = Wc + lHH;
  if (l == 0) {
    Mp[4] = Uf; Mp[5] = Ug; Mp[6] = Uq; Mp[7] = Uc;
  } else {
    const size_t o = (size_t)(l - 1) * H * H;
    Mp[4] = UHf + o; Mp[5] = UHg + o; Mp[6] = UHq + o; Mp[7] = UHc + o;
  }

  // ---- one-time weight fetch -> bf16x2 packed registers (128 regs) --------
  // wpk[mi][ri][q] holds cols {2*lane+128q (lo), +1 (hi)} of row r0+ri.
  unsigned wpk[8][2][8];
#pragma unroll
  for (int mi = 0; mi < 8; ++mi)
#pragma unroll
    for (int ri = 0; ri < 2; ++ri) {
      const float* rowp = Mp[mi] + (size_t)(r0 + ri) * H + 2 * lane;
#pragma unroll
      for (int q = 0; q < 8; ++q) {
        float2 w2 = *(const float2*)(rowp + 128 * q);
        wpk[mi][ri][q] = bf16rne(w2.x) | (bf16rne(w2.y) << 16);
      }
    }

  float bias[4][2];
#pragma unroll
  for (int ri = 0; ri < 2; ++ri) {
    bias[0][ri] = Bf[(size_t)l * H + r0 + ri];
    bias[1][ri] = Bg[(size_t)l * H + r0 + ri];
    bias[2][ri] = Bq[(size_t)l * H + r0 + ri];
    bias[3][ri] = Bc[(size_t)l * H + r0 + ri];
  }

  float sreg[2] = {0.0f, 0.0f};  // cell state for this wave's 2 rows

  __shared__ alignas(16) float hAsh[H];  // own h(t-1)
  __shared__ alignas(16) float hBsh[H];  // layer-0: x_t ; else h_below(t)

  __threadfence();
  grid.sync();   // one-time: init visible everywhere

  const u32* mb = mbox + (size_t)blockIdx.x * MBS;

  for (int t = 0; t < TSEQ; ++t) {
    const u32 tu = (u32)t;
    // ---- dataflow gate: wave 0 polls ITS OWN mailbox slots ---------------
    if (wv == 0) {
      for (;;) {
        bool c = true;
        if (t > 0)               c =      (ldAgent(&mb[lane])       >= tu);
        if (l > 0)               c = c && (ldAgent(&mb[64 + lane])  >= tu + 1);
        if (l < L - 1 && t >= 4) c = c && (ldAgent(&mb[128 + lane]) >= tu - 3);
        if (__all(c)) break;
        __builtin_amdgcn_s_sleep(1);
      }
    }
    __syncthreads();
    __builtin_amdgcn_sched_barrier(0);

    // ---- stage h vectors into LDS: coalesced 16B bypass loads ------------
    {
      if (tid < 256) {
        const float* srcA = hbuf + ((size_t)((t - 1) & (NBUF - 1)) * L + l) * H;
        float4 v = ldBypass16(srcA + 4 * tid);
        ((float4*)hAsh)[tid] = v;
      } else {
        const int j = tid - 256;
        float4 v;
        if (l == 0) {
          v = *(const float4*)(X + (size_t)t * H + 4 * j);
        } else {
          const float* srcB = hbuf + ((size_t)(t & (NBUF - 1)) * L + (l - 1)) * H;
          v = ldBypass16(srcB + 4 * j);
        }
        ((float4*)hBsh)[j] = v;
      }
    }
    __syncthreads();

    // ---- per-lane slices from LDS (conflict-free b64 pattern) ------------
    float ha[16], hb[16];
#pragma unroll
    for (int q = 0; q < 8; ++q) {
      u64 va = ((const u64*)hAsh)[lane + 64 * q];
      ha[2 * q]     = __uint_as_float((u32)va);
      ha[2 * q + 1] = __uint_as_float((u32)(va >> 32));
      u64 vb = ((const u64*)hBsh)[lane + 64 * q];
      hb[2 * q]     = __uint_as_float((u32)vb);
      hb[2 * q + 1] = __uint_as_float((u32)(vb >> 32));
    }

    float acc[4][2];
#pragma unroll
    for (int g = 0; g < 4; ++g)
#pragma unroll
      for (int ri = 0; ri < 2; ++ri) {
        float a = 0.0f;
#pragma unroll
        for (int q = 0; q < 8; ++q) {
          const unsigned wA = wpk[g][ri][q];         // W-side (recurrent)
          a = fmaf(__uint_as_float(wA << 16),         ha[2 * q],     a);
          a = fmaf(__uint_as_float(wA & 0xffff0000u), ha[2 * q + 1], a);
          const unsigned wB = wpk[4 + g][ri][q];     // U-side (input/below)
          a = fmaf(__uint_as_float(wB << 16),         hb[2 * q],     a);
          a = fmaf(__uint_as_float(wB & 0xffff0000u), hb[2 * q + 1], a);
        }
        acc[g][ri] = a;
      }

#pragma unroll
    for (int g = 0; g < 4; ++g)
#pragma unroll
      for (int ri = 0; ri < 2; ++ri) acc[g][ri] = waveSum(acc[g][ri]);

    // all lanes hold the reduced sums -> compute both rows, lane 0 stores 8B
    float hN[2];
#pragma unroll
    for (int ri = 0; ri < 2; ++ri) {
      float f  = sigmoidf_(bias[0][ri] + acc[0][ri]);
      float g_ = sigmoidf_(bias[1][ri] + acc[1][ri]);
      float q_ = sigmoidf_(bias[2][ri] + acc[2][ri]);
      float cd = sigmoidf_(bias[3][ri] + acc[3][ri]);
      float sN = f * sreg[ri] + g_ * cd;
      sreg[ri] = sN;
      hN[ri] = tanhf(sN) * q_;
    }
    if (lane == 0) {
      u64 pk = (u64)__float_as_uint(hN[0]) |
               ((u64)__float_as_uint(hN[1]) << 32);
      stAgentU64((u64*)&hbuf[((size_t)(t & (NBUF - 1)) * L + l) * H + r0], pk);
      if (t == TSEQ - 1) {
        out[(size_t)l * H + r0]     = hN[0];
        out[(size_t)l * H + r0 + 1] = hN[1];
      }
    }

    // __syncthreads drains vmcnt per wave -> this block's h stores have all
    // landed at the coherence point; then wave 0 pushes notifications.
    __syncthreads();
    if (wv == 0) {
      const u32 v = tu + 1;
      // own-layer consumers (their slot [wgl] in region 0)
      stAgentU(mbox + (size_t)(l * WPL + lane) * MBS + wgl, v);
      // above-layer consumers' "below" region
      if (l < L - 1)
        stAgentU(mbox + (size_t)((l + 1) * WPL + lane) * MBS + 64 + wgl, v);
      // below-layer consumers' "WAR" region
      if (l > 0)
        stAgentU(mbox + (size_t)((l - 1) * WPL + lane) * MBS + 128 + wgl, v);
    }
  }
}

// ---------------- launch ----------------------------------------------------
extern "C" void kernel_launch(void* const* d_in, const int* in_sizes, int n_in,
                              void* d_out, int out_size, void* d_ws, size_t ws_size,
                              hipStream_t stream) {
  const float* x   = (const float*)d_in[0];
  const float* Uf  = (const float*)d_in[1];
  const float* UHf = (const float*)d_in[2];
  const float* Wf  = (const float*)d_in[3];
  const float* Bf  = (const float*)d_in[4];
  const float* Ug  = (const float*)d_in[5];
  const float* UHg = (const float*)d_in[6];
  const float* Wg  = (const float*)d_in[7];
  const float* Bg  = (const float*)d_in[8];
  const float* Uq  = (const float*)d_in[9];
  const float* UHq = (const float*)d_in[10];
  const float* Wq  = (const float*)d_in[11];
  const float* Bq  = (const float*)d_in[12];
  const float* Uc  = (const float*)d_in[13];
  const float* UHc = (const float*)d_in[14];
  const float* Wc  = (const float*)d_in[15];
  const float* Bc  = (const float*)d_in[16];
  float* out = (float*)d_out;

  float* hbuf = (float*)d_ws;                                       // 64 KB
  u32*   mbox = (u32*)((char*)d_ws + NBUF * L * H * sizeof(float)); // 192 KB

  void* args[] = { (void*)&x,
                   (void*)&Uf, (void*)&Ug, (void*)&Uq, (void*)&Uc,
                   (void*)&UHf, (void*)&UHg, (void*)&UHq, (void*)&UHc,
                   (void*)&Wf, (void*)&Wg, (void*)&Wq, (void*)&Wc,
                   (void*)&Bf, (void*)&Bg, (void*)&Bq, (void*)&Bc,
                   (void*)&hbuf, (void*)&mbox, (void*)&out };
  hipLaunchCooperativeKernel(reinterpret_cast<void*>(lstm_seq),
                             dim3(NWG), dim3(NTH), args, 0, stream);
}